// Round 12
// baseline (36.558 us; speedup 1.0000x reference)
//
#include <hip/hip_runtime.h>

// ColBERT maxsim via MFMA + compaction + k-split 2-round grid.
// out[b] = sum_q max_k ( mask[b,k] ? <D[b,k,:], Q[b/8,q,:]> : -9999 )
// B*NWAY=1024 docs, DLEN=220, QLEN=32, DIM=128.
//
// Round-11 model: compacted reads realize ~3.1 TB/s vs dense 4.45 (HBM
// activate-rate physics on ~512B scattered granules, ~0.69x). The remaining
// addressable slack is phase serialization: 1024 blocks = exactly ONE round,
// so mask-latency -> compact -> stage -> drain -> compute is globally
// synchronized, plus an nc-variance tail. Round-12: split each doc's kept
// rows across 2 blocks (2048 blocks = TWO rounds): round-2 prologues overlap
// round-1 stage/compute; finer grain shrinks the tail. Partial per-q maxes
// (32 f32/block) -> d_ws (1024x64 f32, fully rewritten each launch ->
// deterministic, no atomics); tiny combine kernel does max-of-2 + sum-of-32.
//
// Kept from the ladder: mask-load-first, Q loads under mask latency, ballot
// compaction (exact: masked rows never win the max), single fully-unrolled
// <=14-deep staging batch, XOR swizzle byte^=((row&7)<<4) on 256B bf16 LDS
// rows (kills 32-way ds_read_b128 conflicts), XCD swizzle (pairs adjacent ->
// both halves + shared Q on one XCD's L2), 256thr/4 blocks/CU.
// MFMA mfma_f32_32x32x16_bf16; same k-map for A and B => layout-safe.
// C/D layout (m74/m101): col(q)=lane&31, row(token)=(reg&3)+8*(reg>>2)+4*g.

#define QLEN   32
#define DIM    128
#define DLEN   220
#define NWAVES 4
#define HROWS  110        // max kept rows per half-block

typedef __attribute__((ext_vector_type(8)))  short bf16x8;
typedef __attribute__((ext_vector_type(16))) float f32x16;

__device__ __forceinline__ short f2bf(float f) {
    __bf16 h = (__bf16)f;                      // RNE hardware convert
    return __builtin_bit_cast(short, h);
}

__device__ __forceinline__ short4 cvt4(const float4& v) {
    short4 s;
    s.x = f2bf(v.x); s.y = f2bf(v.y); s.z = f2bf(v.z); s.w = f2bf(v.w);
    return s;
}

__device__ __forceinline__ bf16x8 cvt8(const float4& a, const float4& b) {
    bf16x8 r;
    r[0] = f2bf(a.x); r[1] = f2bf(a.y); r[2] = f2bf(a.z); r[3] = f2bf(a.w);
    r[4] = f2bf(b.x); r[5] = f2bf(b.y); r[6] = f2bf(b.z); r[7] = f2bf(b.w);
    return r;
}

__global__ __launch_bounds__(256, 4)
void colbert_part(const float* __restrict__ Q,
                  const float* __restrict__ D,
                  const int*   __restrict__ Dm,
                  float* __restrict__ ws)
{
    const int o = blockIdx.x;           // 0..2047
    const int h = o & 1;                // half index (adjacent -> co-dispatch)
    const int p = o >> 1;               // doc pair id, 0..1023
    // XCD swizzle over the 1024 docs (bijective, 1024 % 8 == 0)
    const int cpx = (gridDim.x >> 1) >> 3;       // 128
    const int b   = (p & 7) * cpx + (p >> 3);

    const int tid  = threadIdx.x;
    const int wave = tid >> 6;
    const int lane = tid & 63;
    const int qb   = b >> 3;            // nway = 8

    const int col = lane & 31;          // A row-in-tile / B col (q)
    const int g   = lane >> 5;          // k-group

    __shared__ __align__(16) short dl[HROWS * DIM];  // 28160 B staged bf16 rows
    __shared__ short list[DLEN + 4];                  // compacted row indices
    __shared__ int   wcnt[NWAVES];
    __shared__ int   s_nc;
    __shared__ float red[NWAVES][QLEN];

    const float* __restrict__ dbase = D + (size_t)b * DLEN * DIM;

    // ---- 1. mask load FIRST: heads the dependency chain ----
    int mv = 0;
    if (tid < DLEN) mv = Dm[(size_t)b * DLEN + tid];

    // ---- 2. Q loads issued under the mask latency ----
    const float* __restrict__ qrow = Q + ((size_t)qb * QLEN + col) * DIM;
    float4 qx[8], qy[8];
#pragma unroll
    for (int ks = 0; ks < 8; ++ks) {
        qx[ks] = *reinterpret_cast<const float4*>(qrow + ks * 16 + g * 8);
        qy[ks] = *reinterpret_cast<const float4*>(qrow + ks * 16 + g * 8 + 4);
    }

    // ---- 3. compact kept row indices (order-preserving) ----
    const unsigned long long bal = __ballot(mv > 0);
    const int prefix = __popcll(bal & ((1ull << lane) - 1ull));
    if (lane == 0) wcnt[wave] = __popcll(bal);
    __syncthreads();
    int base = 0;
#pragma unroll
    for (int w = 0; w < NWAVES; ++w) base += (w < wave) ? wcnt[w] : 0;
    if (mv > 0) list[base + prefix] = (short)tid;
    if (tid == 0) s_nc = wcnt[0] + wcnt[1] + wcnt[2] + wcnt[3];

    // Q cvt overlaps the compaction barrier
    bf16x8 bq[8];
#pragma unroll
    for (int ks = 0; ks < 8; ++ks) bq[ks] = cvt8(qx[ks], qy[ks]);
    __syncthreads();

    // ---- my half of the kept rows ----
    const int nc    = s_nc;
    const int half0 = (nc + 1) >> 1;
    const int lo    = h ? half0 : 0;
    const int rows  = h ? (nc - half0) : half0;   // <= 110

    float best = -9999.0f;

    if (rows > 0) {
        const int nch = rows * 32;       // 16B chunks, <= 3520

        // ---- 4. indices->regs, ONE fully-unrolled <=14-deep batch ----
        short rrow[14];
#pragma unroll
        for (int u = 0; u < 14; ++u) {
            const int c  = tid + u * 256;
            const int cl = (c < nch) ? c : (nch - 1);
            rrow[u] = list[lo + (cl >> 5)];
        }
        float4 v[14];
#pragma unroll
        for (int u = 0; u < 14; ++u) {               // dense deep issue
            const int cir = (tid + u * 256) & 31;
            v[u] = *reinterpret_cast<const float4*>(
                       dbase + (size_t)rrow[u] * DIM + cir * 4);
        }
#pragma unroll
        for (int u = 0; u < 14; ++u) {               // predicated writes
            const int c = tid + u * 256;
            if (c < nch) {
                const int lr = c >> 5, cir = c & 31;
                const int byte = lr * 256 + ((cir * 8) ^ ((lr & 7) << 4));
                *reinterpret_cast<short4*>(reinterpret_cast<char*>(dl) + byte)
                    = cvt4(v[u]);
            }
        }
        __syncthreads();

        // ---- 5. compute: ceil(rows/32) <= 4 tiles, one per wave ----
        const int ntiles = (rows + 31) >> 5;
        if (wave < ntiles) {
            const int tloc = wave * 32;
            int rloc = tloc + col;
            if (rloc >= rows) rloc = 0;              // clamp; rejected below
            const int rsw = (rloc & 7) << 4;
            f32x16 acc = {};
#pragma unroll
            for (int ks = 0; ks < 8; ++ks) {
                const int byte = rloc * 256 + ((ks * 32 + g * 16) ^ rsw);
                const bf16x8 a = *reinterpret_cast<const bf16x8*>(
                                     reinterpret_cast<const char*>(dl) + byte);
                acc = __builtin_amdgcn_mfma_f32_32x32x16_bf16(a, bq[ks], acc, 0, 0, 0);
            }
            // validity: local staged slot < rows (mask already applied)
#pragma unroll
            for (int p4 = 0; p4 < 4; ++p4) {
                const int i4 = tloc + p4 * 8 + g * 4;
                const float v0 = (i4 + 0 < rows) ? acc[4 * p4 + 0] : -9999.0f;
                const float v1 = (i4 + 1 < rows) ? acc[4 * p4 + 1] : -9999.0f;
                const float v2 = (i4 + 2 < rows) ? acc[4 * p4 + 2] : -9999.0f;
                const float v3 = (i4 + 3 < rows) ? acc[4 * p4 + 3] : -9999.0f;
                best = fmaxf(best, fmaxf(fmaxf(v0, v1), fmaxf(v2, v3)));
            }
        }
    }

    // combine the two k-group token-halves (lanes l and l^32 share q=col)
    best = fmaxf(best, __shfl_xor(best, 32, 64));

    // ---- cross-wave max, then write 32 partial maxes to workspace ----
    if (lane < 32) red[wave][col] = best;
    __syncthreads();

    if (tid < QLEN) {
        float m = fmaxf(fmaxf(red[0][tid], red[1][tid]),
                        fmaxf(red[2][tid], red[3][tid]));
        ws[(size_t)b * 64 + h * 32 + tid] = m;
    }
}

// max-of-2-halves per q, then sum over the 32 q's. 8 docs per 256-thr block.
__global__ __launch_bounds__(256)
void colbert_combine(const float* __restrict__ ws, float* __restrict__ out)
{
    const int tid = threadIdx.x;
    const int d   = blockIdx.x * 8 + (tid >> 5);   // doc
    const int q   = tid & 31;
    float m = fmaxf(ws[(size_t)d * 64 + q], ws[(size_t)d * 64 + 32 + q]);
#pragma unroll
    for (int off = 16; off > 0; off >>= 1)         // stays within 32-lane group
        m += __shfl_xor(m, off, 64);
    if (q == 0) out[d] = m;
}

extern "C" void kernel_launch(void* const* d_in, const int* in_sizes, int n_in,
                              void* d_out, int out_size, void* d_ws, size_t ws_size,
                              hipStream_t stream)
{
    const float* Q  = (const float*)d_in[0];
    const float* D  = (const float*)d_in[1];
    const int*   Dm = (const int*)d_in[2];
    float* outp = (float*)d_out;
    float* wsf  = (float*)d_ws;        // needs 1024*64*4 = 256 KB scratch
    const int ndocs = out_size;        // B*NWAY = 1024

    colbert_part<<<ndocs * 2, NWAVES * 64, 0, stream>>>(Q, D, Dm, wsf);
    colbert_combine<<<ndocs / 8, 256, 0, stream>>>(wsf, outp);
}

// Round 13
// 21.690 us; speedup vs baseline: 1.6854x; 1.6854x over previous
//
#include <hip/hip_runtime.h>

// ColBERT maxsim via MFMA + masked-row compaction + deep-issue staging (R9
// champion + drain fix).
// out[b] = sum_q max_k ( mask[b,k] ? <D[b,k,:], Q[b/8,q,:]> : -9999 )
// B*NWAY=1024 docs, DLEN=220, QLEN=32, DIM=128.
//
// Model after 12 rounds: dense streams ~4.45 TB/s; row-compacted scattered
// streams wall at ~3.1 TB/s (DRAM activate-rate on ~512B granules @ 50%
// density; 3 independent impls R8/R9/R11 all 2.8-3.1). Compaction still nets
// out: 61 MB @ 3.1 < 117 MB @ 4.45. R10 (2 big blocks/CU), R11 (direct
// gather), R12 (k-split w/ duplicated prologue) all regressed -> R9 shape is
// the best-known. This round: R9 exactly, except the 16 staging loads issue
// as 12-deep + 4-deep with SEPARATE register arrays (R9 reused v[8] twice,
// draining the vmem queue mid-stage and re-paying ~900cy once per block).
//
// Kept: mask-load-first, Q loads under mask latency, ballot compaction
// (exact: masked rows never win the max), XOR swizzle byte^=((row&7)<<4) on
// 256B bf16 LDS rows (kills 32-way ds_read_b128 conflict), XCD swizzle,
// 256thr / 4 waves / 4 blocks/CU.
// MFMA mfma_f32_32x32x16_bf16; same k-map for A and B => layout-safe.
// C/D layout (m74/m101): col(q)=lane&31, row(token)=(reg&3)+8*(reg>>2)+4*g.

#define QLEN   32
#define DIM    128
#define DLEN   220
#define NWAVES 4
#define C0MAX  128

typedef __attribute__((ext_vector_type(8)))  short bf16x8;
typedef __attribute__((ext_vector_type(16))) float f32x16;

__device__ __forceinline__ short f2bf(float f) {
    __bf16 h = (__bf16)f;                      // RNE hardware convert
    return __builtin_bit_cast(short, h);
}

__device__ __forceinline__ short4 cvt4(const float4& v) {
    short4 s;
    s.x = f2bf(v.x); s.y = f2bf(v.y); s.z = f2bf(v.z); s.w = f2bf(v.w);
    return s;
}

__device__ __forceinline__ bf16x8 cvt8(const float4& a, const float4& b) {
    bf16x8 r;
    r[0] = f2bf(a.x); r[1] = f2bf(a.y); r[2] = f2bf(a.z); r[3] = f2bf(a.w);
    r[4] = f2bf(b.x); r[5] = f2bf(b.y); r[6] = f2bf(b.z); r[7] = f2bf(b.w);
    return r;
}

__global__ __launch_bounds__(256, 4)
void colbert_mfma(const float* __restrict__ Q,
                  const float* __restrict__ D,
                  const int*   __restrict__ Dm,
                  float* __restrict__ out)
{
    // XCD swizzle (bijective: gridDim.x = 1024 % 8 == 0): docs sharing a Q
    // tile land on one XCD's L2.
    const int cpx = gridDim.x >> 3;
    const int o   = blockIdx.x;
    const int b   = (o & 7) * cpx + (o >> 3);

    const int tid  = threadIdx.x;
    const int wave = tid >> 6;
    const int lane = tid & 63;
    const int qb   = b >> 3;            // nway = 8

    const int col = lane & 31;          // A row-in-tile / B col (q)
    const int g   = lane >> 5;          // k-group

    __shared__ __align__(16) short dl[C0MAX * DIM];   // 32 KB staged bf16 rows
    __shared__ short list[DLEN + 4];                   // compacted row indices
    __shared__ int   wcnt[NWAVES];
    __shared__ int   s_nc;
    __shared__ float red[NWAVES][QLEN];

    const float* __restrict__ dbase = D + (size_t)b * DLEN * DIM;

    // ---- 1. mask load FIRST: heads the dependency chain ----
    int mv = 0;
    if (tid < DLEN) mv = Dm[(size_t)b * DLEN + tid];

    // ---- 2. Q loads issued under the mask latency ----
    const float* __restrict__ qrow = Q + ((size_t)qb * QLEN + col) * DIM;
    float4 qx[8], qy[8];
#pragma unroll
    for (int ks = 0; ks < 8; ++ks) {
        qx[ks] = *reinterpret_cast<const float4*>(qrow + ks * 16 + g * 8);
        qy[ks] = *reinterpret_cast<const float4*>(qrow + ks * 16 + g * 8 + 4);
    }

    // ---- 3. compact kept row indices (order-preserving) ----
    const unsigned long long bal = __ballot(mv > 0);
    const int prefix = __popcll(bal & ((1ull << lane) - 1ull));
    if (lane == 0) wcnt[wave] = __popcll(bal);
    __syncthreads();
    int base = 0;
#pragma unroll
    for (int w = 0; w < NWAVES; ++w) base += (w < wave) ? wcnt[w] : 0;
    if (mv > 0) list[base + prefix] = (short)tid;
    if (tid == 0) s_nc = wcnt[0] + wcnt[1] + wcnt[2] + wcnt[3];

    // Q cvt overlaps the compaction barrier (frees 64 VGPR before D staging)
    bf16x8 bq[8];
#pragma unroll
    for (int ks = 0; ks < 8; ++ks) bq[ks] = cvt8(qx[ks], qy[ks]);
    __syncthreads();

    const int nc = s_nc;                 // kept rows, ~Binom(220,1/2) ~ 110
    const int c0 = (nc < C0MAX) ? nc : C0MAX;

    float best = -9999.0f;

    if (c0 > 0) {
        const int nch = c0 * 32;         // 16B chunks in chunk0

        // ---- 4. indices->regs, then 12-deep + 4-deep issue (separate regs:
        //         no mid-stage vmem-queue drain) ----
        short rrow[16];
#pragma unroll
        for (int u = 0; u < 16; ++u) {
            const int c = tid + u * 256;
            rrow[u] = list[(c < nch ? c : 0) >> 5];
        }
        float4 v1[12];
#pragma unroll
        for (int u = 0; u < 12; ++u) {                // dense 12-deep issue
            const int cir = (tid + u * 256) & 31;
            v1[u] = *reinterpret_cast<const float4*>(
                        dbase + (size_t)rrow[u] * DIM + cir * 4);
        }
        float4 v2[4];
#pragma unroll
        for (int u = 0; u < 4; ++u) {                 // tail issues before drain
            const int uu = 12 + u;
            const int cir = (tid + uu * 256) & 31;
            v2[u] = *reinterpret_cast<const float4*>(
                        dbase + (size_t)rrow[uu] * DIM + cir * 4);
        }
#pragma unroll
        for (int u = 0; u < 12; ++u) {                // predicated writes
            const int c = tid + u * 256;
            if (c < nch) {
                const int lr = c >> 5, cir = c & 31;
                const int byte = lr * 256 + ((cir * 8) ^ ((lr & 7) << 4));
                *reinterpret_cast<short4*>(reinterpret_cast<char*>(dl) + byte)
                    = cvt4(v1[u]);
            }
        }
#pragma unroll
        for (int u = 0; u < 4; ++u) {
            const int c = tid + (12 + u) * 256;
            if (c < nch) {
                const int lr = c >> 5, cir = c & 31;
                const int byte = lr * 256 + ((cir * 8) ^ ((lr & 7) << 4));
                *reinterpret_cast<short4*>(reinterpret_cast<char*>(dl) + byte)
                    = cvt4(v2[u]);
            }
        }
        __syncthreads();

        // ---- 5. compute chunk0: ceil(c0/32) tiles, one per wave ----
        const int ntiles = (c0 + 31) >> 5;
        if (wave < ntiles) {
            const int tloc = wave * 32;
            int rloc = tloc + col;
            if (rloc >= c0) rloc = 0;              // clamp; rejected below
            const int rsw = (rloc & 7) << 4;
            f32x16 acc = {};
#pragma unroll
            for (int ks = 0; ks < 8; ++ks) {
                const int byte = rloc * 256 + ((ks * 32 + g * 16) ^ rsw);
                const bf16x8 a = *reinterpret_cast<const bf16x8*>(
                                     reinterpret_cast<const char*>(dl) + byte);
                acc = __builtin_amdgcn_mfma_f32_32x32x16_bf16(a, bq[ks], acc, 0, 0, 0);
            }
            // validity: compacted local index < c0 (mask already applied)
#pragma unroll
            for (int p = 0; p < 4; ++p) {
                const int i4 = tloc + p * 8 + g * 4;
                const float v0 = (i4 + 0 < c0) ? acc[4 * p + 0] : -9999.0f;
                const float vv1 = (i4 + 1 < c0) ? acc[4 * p + 1] : -9999.0f;
                const float vv2 = (i4 + 2 < c0) ? acc[4 * p + 2] : -9999.0f;
                const float vv3 = (i4 + 3 < c0) ? acc[4 * p + 3] : -9999.0f;
                best = fmaxf(best, fmaxf(fmaxf(v0, vv1), fmaxf(vv2, vv3)));
            }
        }
    }

    // ---- rare chunk1 (nc > 128; ~0.7% of docs): simple rolled flow ----
    const int cr1 = nc - c0;
    if (cr1 > 0) {
        __syncthreads();                 // chunk0 reads done before overwrite
        const int nch = cr1 * 32;
        for (int i = tid; i < nch; i += 256) {
            const int row = list[c0 + (i >> 5)], cir = i & 31;
            const float4 vv = *reinterpret_cast<const float4*>(
                                  dbase + (size_t)row * DIM + cir * 4);
            const int lr = i >> 5;
            const int byte = lr * 256 + ((cir * 8) ^ ((lr & 7) << 4));
            *reinterpret_cast<short4*>(reinterpret_cast<char*>(dl) + byte) = cvt4(vv);
        }
        __syncthreads();

        const int ntiles = (cr1 + 31) >> 5;
        if (wave < ntiles) {
            const int tloc = wave * 32;
            int rloc = tloc + col;
            if (rloc >= cr1) rloc = 0;
            const int rsw = (rloc & 7) << 4;
            f32x16 acc = {};
#pragma unroll
            for (int ks = 0; ks < 8; ++ks) {
                const int byte = rloc * 256 + ((ks * 32 + g * 16) ^ rsw);
                const bf16x8 a = *reinterpret_cast<const bf16x8*>(
                                     reinterpret_cast<const char*>(dl) + byte);
                acc = __builtin_amdgcn_mfma_f32_32x32x16_bf16(a, bq[ks], acc, 0, 0, 0);
            }
#pragma unroll
            for (int p = 0; p < 4; ++p) {
                const int i4 = tloc + p * 8 + g * 4;
                const float v0 = (i4 + 0 < cr1) ? acc[4 * p + 0] : -9999.0f;
                const float vv1 = (i4 + 1 < cr1) ? acc[4 * p + 1] : -9999.0f;
                const float vv2 = (i4 + 2 < cr1) ? acc[4 * p + 2] : -9999.0f;
                const float vv3 = (i4 + 3 < cr1) ? acc[4 * p + 3] : -9999.0f;
                best = fmaxf(best, fmaxf(fmaxf(v0, vv1), fmaxf(vv2, vv3)));
            }
        }
    }

    // combine the two k-group token-halves (lanes l and l^32 share q=col)
    best = fmaxf(best, __shfl_xor(best, 32, 64));

    // ---- cross-wave max, then sum over q ----
    if (lane < 32) red[wave][col] = best;
    __syncthreads();

    if (tid < QLEN) {
        float m = red[0][tid];
#pragma unroll
        for (int w = 1; w < NWAVES; ++w) m = fmaxf(m, red[w][tid]);
#pragma unroll
        for (int off = 16; off > 0; off >>= 1) m += __shfl_xor(m, off, 32);
        if (tid == 0) out[b] = m;
    }
}

extern "C" void kernel_launch(void* const* d_in, const int* in_sizes, int n_in,
                              void* d_out, int out_size, void* d_ws, size_t ws_size,
                              hipStream_t stream)
{
    const float* Q  = (const float*)d_in[0];
    const float* D  = (const float*)d_in[1];
    const int*   Dm = (const int*)d_in[2];
    float* outp = (float*)d_out;
    const int ndocs = out_size;   // B*NWAY = 1024
    colbert_mfma<<<ndocs, NWAVES * 64, 0, stream>>>(Q, D, Dm, outp);
}

// Round 14
// 20.132 us; speedup vs baseline: 1.8159x; 1.0774x over previous
//
#include <hip/hip_runtime.h>

// ColBERT maxsim via MFMA + masked-row compaction + deep-issue staging.
// out[b] = sum_q max_k ( mask[b,k] ? <D[b,k,:], Q[b/8,q,:]> : -9999 )
// B*NWAY=1024 docs, DLEN=220, QLEN=32, DIM=128.
//
// === R9 CHAMPION RESTORED (19.95 us) ===
// Final model after 13 rounds:
//  - dense D streams realize ~4.45 TB/s (R5/R7: 26.5 us on 117 MB);
//  - 50%-density compacted row reads wall at ~3.1 TB/s (R8/R9/R11/R13 all
//    2.8-3.1): ~every DRAM page still activates while bytes halve ->
//    bytes/activate halves (access-pattern physics, not scheduling);
//  - compaction nets positive: 61 MB @ 3.06 = 19.95 us < 117 @ 4.45 = 26.5.
// Structural bets that LOST to this shape: 512-thr blocks (R10, -38%),
// direct gather of compacted rows (R11, -10%), k-split 2-round grid with
// duplicated prologue (R12, -83%), 12+4 staging split at the VGPR cap
// (R13, -9%). Byte floor x rate wall ~= 19.5-20 us -> this is the practical
// roofline for this op on MI355X.
//
// Structure: 256 thr / 4 waves / 4 blocks/CU; mask load first (heads dep
// chain), Q strided loads under mask latency, ballot compaction (exact:
// masked rows never win the max; -9999 init reproduces all-masked docs),
// row indices list->regs then two fully-unrolled 8-deep load batches,
// XOR swizzle byte^=((row&7)<<4) on 256B bf16 LDS rows (kills the 32-way
// ds_read_b128 bank conflict), XCD swizzle for Q L2-locality, rare chunk1
// path for nc>128 (~0.7% of docs).
// MFMA mfma_f32_32x32x16_bf16; same k-map (k=ks*16+g*8+j) for A and B =>
// layout-safe (dot products K-permutation invariant).
// C/D layout (m74/m101): col(q)=lane&31, row(token)=(reg&3)+8*(reg>>2)+4*g.

#define QLEN   32
#define DIM    128
#define DLEN   220
#define NWAVES 4
#define C0MAX  128

typedef __attribute__((ext_vector_type(8)))  short bf16x8;
typedef __attribute__((ext_vector_type(16))) float f32x16;

__device__ __forceinline__ short f2bf(float f) {
    __bf16 h = (__bf16)f;                      // RNE hardware convert
    return __builtin_bit_cast(short, h);
}

__device__ __forceinline__ short4 cvt4(const float4& v) {
    short4 s;
    s.x = f2bf(v.x); s.y = f2bf(v.y); s.z = f2bf(v.z); s.w = f2bf(v.w);
    return s;
}

__device__ __forceinline__ bf16x8 cvt8(const float4& a, const float4& b) {
    bf16x8 r;
    r[0] = f2bf(a.x); r[1] = f2bf(a.y); r[2] = f2bf(a.z); r[3] = f2bf(a.w);
    r[4] = f2bf(b.x); r[5] = f2bf(b.y); r[6] = f2bf(b.z); r[7] = f2bf(b.w);
    return r;
}

__global__ __launch_bounds__(256, 4)
void colbert_mfma(const float* __restrict__ Q,
                  const float* __restrict__ D,
                  const int*   __restrict__ Dm,
                  float* __restrict__ out)
{
    // XCD swizzle (bijective: gridDim.x = 1024 % 8 == 0): docs sharing a Q
    // tile land on one XCD's L2.
    const int cpx = gridDim.x >> 3;
    const int o   = blockIdx.x;
    const int b   = (o & 7) * cpx + (o >> 3);

    const int tid  = threadIdx.x;
    const int wave = tid >> 6;
    const int lane = tid & 63;
    const int qb   = b >> 3;            // nway = 8

    const int col = lane & 31;          // A row-in-tile / B col (q)
    const int g   = lane >> 5;          // k-group

    __shared__ __align__(16) short dl[C0MAX * DIM];   // 32 KB staged bf16 rows
    __shared__ short list[DLEN + 4];                   // compacted row indices
    __shared__ int   wcnt[NWAVES];
    __shared__ int   s_nc;
    __shared__ float red[NWAVES][QLEN];

    const float* __restrict__ dbase = D + (size_t)b * DLEN * DIM;

    // ---- 1. mask load FIRST: it heads the dependency chain ----
    int mv = 0;
    if (tid < DLEN) mv = Dm[(size_t)b * DLEN + tid];

    // ---- 2. Q loads issued under the mask latency ----
    const float* __restrict__ qrow = Q + ((size_t)qb * QLEN + col) * DIM;
    float4 qx[8], qy[8];
#pragma unroll
    for (int ks = 0; ks < 8; ++ks) {
        qx[ks] = *reinterpret_cast<const float4*>(qrow + ks * 16 + g * 8);
        qy[ks] = *reinterpret_cast<const float4*>(qrow + ks * 16 + g * 8 + 4);
    }

    // ---- 3. compact kept row indices (order-preserving) ----
    const unsigned long long bal = __ballot(mv > 0);
    const int prefix = __popcll(bal & ((1ull << lane) - 1ull));
    if (lane == 0) wcnt[wave] = __popcll(bal);
    __syncthreads();
    int base = 0;
#pragma unroll
    for (int w = 0; w < NWAVES; ++w) base += (w < wave) ? wcnt[w] : 0;
    if (mv > 0) list[base + prefix] = (short)tid;
    if (tid == 0) s_nc = wcnt[0] + wcnt[1] + wcnt[2] + wcnt[3];

    // Q cvt overlaps the compaction barrier (frees 64 VGPR before D staging)
    bf16x8 bq[8];
#pragma unroll
    for (int ks = 0; ks < 8; ++ks) bq[ks] = cvt8(qx[ks], qy[ks]);
    __syncthreads();

    const int nc = s_nc;                 // kept rows, ~Binom(220,1/2) ~ 110
    const int c0 = (nc < C0MAX) ? nc : C0MAX;

    float best = -9999.0f;

    if (c0 > 0) {
        const int nch = c0 * 32;         // 16B chunks in chunk0

        // ---- 4. row indices -> registers, then 2 x 8-deep unrolled issue ----
        short rrow[16];
#pragma unroll
        for (int u = 0; u < 16; ++u) {
            const int c = tid + u * 256;
            rrow[u] = list[(c < nch ? c : 0) >> 5];
        }
#pragma unroll
        for (int half = 0; half < 2; ++half) {
            float4 v[8];
#pragma unroll
            for (int u = 0; u < 8; ++u) {                 // dense 8-deep issue
                const int uu = half * 8 + u;
                const int cir = (tid + uu * 256) & 31;
                v[u] = *reinterpret_cast<const float4*>(
                           dbase + (size_t)rrow[uu] * DIM + cir * 4);
            }
#pragma unroll
            for (int u = 0; u < 8; ++u) {                 // predicated writes
                const int uu = half * 8 + u;
                const int c  = tid + uu * 256;
                if (c < nch) {
                    const int lr = c >> 5, cir = c & 31;
                    const int byte = lr * 256 + ((cir * 8) ^ ((lr & 7) << 4));
                    *reinterpret_cast<short4*>(reinterpret_cast<char*>(dl) + byte)
                        = cvt4(v[u]);
                }
            }
        }
        __syncthreads();

        // ---- 5. compute chunk0: ceil(c0/32) tiles, one per wave ----
        const int ntiles = (c0 + 31) >> 5;
        if (wave < ntiles) {
            const int tloc = wave * 32;
            int rloc = tloc + col;
            if (rloc >= c0) rloc = 0;              // clamp; rejected below
            const int rsw = (rloc & 7) << 4;
            f32x16 acc = {};
#pragma unroll
            for (int ks = 0; ks < 8; ++ks) {
                const int byte = rloc * 256 + ((ks * 32 + g * 16) ^ rsw);
                const bf16x8 a = *reinterpret_cast<const bf16x8*>(
                                     reinterpret_cast<const char*>(dl) + byte);
                acc = __builtin_amdgcn_mfma_f32_32x32x16_bf16(a, bq[ks], acc, 0, 0, 0);
            }
            // validity: compacted local index < c0 (mask already applied)
#pragma unroll
            for (int p = 0; p < 4; ++p) {
                const int i4 = tloc + p * 8 + g * 4;
                const float v0 = (i4 + 0 < c0) ? acc[4 * p + 0] : -9999.0f;
                const float v1 = (i4 + 1 < c0) ? acc[4 * p + 1] : -9999.0f;
                const float v2 = (i4 + 2 < c0) ? acc[4 * p + 2] : -9999.0f;
                const float v3 = (i4 + 3 < c0) ? acc[4 * p + 3] : -9999.0f;
                best = fmaxf(best, fmaxf(fmaxf(v0, v1), fmaxf(v2, v3)));
            }
        }
    }

    // ---- rare chunk1 (nc > 128; ~0.7% of docs): simple rolled flow ----
    const int cr1 = nc - c0;
    if (cr1 > 0) {
        __syncthreads();                 // chunk0 reads done before overwrite
        const int nch = cr1 * 32;
        for (int i = tid; i < nch; i += 256) {
            const int row = list[c0 + (i >> 5)], cir = i & 31;
            const float4 v = *reinterpret_cast<const float4*>(
                                 dbase + (size_t)row * DIM + cir * 4);
            const int lr = i >> 5;
            const int byte = lr * 256 + ((cir * 8) ^ ((lr & 7) << 4));
            *reinterpret_cast<short4*>(reinterpret_cast<char*>(dl) + byte) = cvt4(v);
        }
        __syncthreads();

        const int ntiles = (cr1 + 31) >> 5;
        if (wave < ntiles) {
            const int tloc = wave * 32;
            int rloc = tloc + col;
            if (rloc >= cr1) rloc = 0;
            const int rsw = (rloc & 7) << 4;
            f32x16 acc = {};
#pragma unroll
            for (int ks = 0; ks < 8; ++ks) {
                const int byte = rloc * 256 + ((ks * 32 + g * 16) ^ rsw);
                const bf16x8 a = *reinterpret_cast<const bf16x8*>(
                                     reinterpret_cast<const char*>(dl) + byte);
                acc = __builtin_amdgcn_mfma_f32_32x32x16_bf16(a, bq[ks], acc, 0, 0, 0);
            }
#pragma unroll
            for (int p = 0; p < 4; ++p) {
                const int i4 = tloc + p * 8 + g * 4;
                const float v0 = (i4 + 0 < cr1) ? acc[4 * p + 0] : -9999.0f;
                const float v1 = (i4 + 1 < cr1) ? acc[4 * p + 1] : -9999.0f;
                const float v2 = (i4 + 2 < cr1) ? acc[4 * p + 2] : -9999.0f;
                const float v3 = (i4 + 3 < cr1) ? acc[4 * p + 3] : -9999.0f;
                best = fmaxf(best, fmaxf(fmaxf(v0, v1), fmaxf(v2, v3)));
            }
        }
    }

    // combine the two k-group token-halves (lanes l and l^32 share q=col)
    best = fmaxf(best, __shfl_xor(best, 32, 64));

    // ---- cross-wave max, then sum over q ----
    if (lane < 32) red[wave][col] = best;
    __syncthreads();

    if (tid < QLEN) {
        float m = red[0][tid];
#pragma unroll
        for (int w = 1; w < NWAVES; ++w) m = fmaxf(m, red[w][tid]);
#pragma unroll
        for (int off = 16; off > 0; off >>= 1) m += __shfl_xor(m, off, 32);
        if (tid == 0) out[b] = m;
    }
}

extern "C" void kernel_launch(void* const* d_in, const int* in_sizes, int n_in,
                              void* d_out, int out_size, void* d_ws, size_t ws_size,
                              hipStream_t stream)
{
    const float* Q  = (const float*)d_in[0];
    const float* D  = (const float*)d_in[1];
    const int*   Dm = (const int*)d_in[2];
    float* outp = (float*)d_out;
    const int ndocs = out_size;   // B*NWAY = 1024
    colbert_mfma<<<ndocs, NWAVES * 64, 0, stream>>>(Q, D, Dm, outp);
}